// Round 13
// baseline (109.611 us; speedup 1.0000x reference)
//
#include <hip/hip_runtime.h>
#include <hip/hip_bf16.h>

// B=4, D=8 -> G=32 graphs, N=2000 nodes, E=32000 edges (+N self loops),
// EMB=32, H=4 heads, C=32 -> H*C=128. fp32 I/O (verified round 6).
// R10 finding: hipLaunchCooperativeKernel silently no-ops here.
// R11 finding: ~46 us/call is harness poison fill (256 MiB ws) — fixed cost.
#define NODES  2000
#define GRAPHS 32
#define NEDGE  32000
#define EMBD   32
#define HEADS  4
#define CDIM   32
#define HC     128
#define DCAP   64            // per-dst slot cap; Poisson(16) tail @64 ~1e-20
#define NEG_SLOPE 0.2f

// Static device scratch. Invariant: g_cnt == 0 at entry of every call
// (.bss-zeroed at load; k_reset restores it each call).
__device__ unsigned short g_tb[NODES * HC];     // t rows, bf16 (512 KB)
__device__ float g_ts[NODES * HEADS];           // <t[v,h,:], att_src[h,:]>
__device__ float g_td[NODES * HEADS];           // <t[v,h,:], att_dst[h,:]>
__device__ int   g_cnt[NODES];                  // in-degree / cursor
__device__ int   g_slot[NODES * DCAP];          // src ids per dst

__device__ __forceinline__ float lrelu(float z) {
    return z >= 0.f ? z : NEG_SLOPE * z;
}
__device__ __forceinline__ float bflo(unsigned int w) {
    return __uint_as_float(w << 16);
}
__device__ __forceinline__ float bfhi(unsigned int w) {
    return __uint_as_float(w & 0xffff0000u);
}

// ---------------------------------------------------------------------------
// Launch 1: token tables (blocks 0..999) CONCURRENT with edge slot-scatter
// (blocks 1000..1124).
// ---------------------------------------------------------------------------
__global__ __launch_bounds__(256) void k_prep(
    const float* __restrict__ emb,
    const float* __restrict__ lw,
    const float* __restrict__ asrc,
    const float* __restrict__ adst,
    const int*   __restrict__ adj)
{
    if (blockIdx.x >= NODES / 2) {
        int e = (blockIdx.x - NODES / 2) * 256 + threadIdx.x;   // exact 32000
        int s = adj[e];
        int d = adj[NEDGE + e];
        int pos = atomicAdd(&g_cnt[d], 1);
        if (pos < DCAP) g_slot[d * DCAP + pos] = s;
        return;
    }

    int v = blockIdx.x * 2 + (threadIdx.x >> 7);
    int j = threadIdx.x & 127;          // h = j>>5, c = j&31

    float acc = 0.f;
#pragma unroll
    for (int d = 0; d < EMBD; ++d)
        acc = fmaf(emb[v * EMBD + d], lw[d * HC + j], acc);
    g_tb[v * HC + j] = __bfloat16_as_ushort(__float2bfloat16(acc));

    int h = j >> 5, c = j & 31;
    float ps = acc * asrc[h * CDIM + c];
    float pd = acc * adst[h * CDIM + c];
#pragma unroll
    for (int m = 16; m >= 1; m >>= 1) {
        ps += __shfl_xor(ps, m);
        pd += __shfl_xor(pd, m);
    }
    if (c == 0) {
        g_ts[v * HEADS + h] = ps;
        g_td[v * HEADS + h] = pd;
    }
}

// ---------------------------------------------------------------------------
// Launch 2: main GAT kernel. Block b: node n = b>>1 (scalar deg/slots),
// graphs gset = (b&1)*16 .. +15 (16 thr each; thread t: head h=t>>2,
// cols j0 = t*8 -> one dwordx4 per bf16 row).
// Phase A: ALL per-edge scalars — token ids AND softmax weights
// w = exp(lrelu(ts_src + td_dst)) — computed in parallel by 256 threads
// (deg*16 independent (p,g) pairs) into LDS. One barrier.
// Phase B: edge loop with NO dependent L2 chain: tokens from LDS (+6),
// rows prefetched +4 (registers), weights from LDS (+2). No tail masking
// (loop trips == deg, block-uniform; per-p weights exact).
// Single pass softmax (|logit| < ~15 -> exp safe; ratio identical).
// ---------------------------------------------------------------------------
__global__ __launch_bounds__(256) void k_main(
    const int* __restrict__ x,
    const float* __restrict__ bias,
    float* __restrict__ out)
{
    __shared__ float l_w[DCAP * 16 * 4];    // [(p*16+g)*4 + h]  16 KB
    __shared__ int   l_tok[DCAP * 16];      // [p*16 + g]         4 KB

    int b = blockIdx.x;
    int n = b >> 1;                          // block-uniform node
    int gset = (b & 1) << 4;

    int deg = g_cnt[n];                      // scalar
    if (deg > DCAP) deg = DCAP;
    const int* sl = g_slot + n * DCAP;       // scalar base

    // ---- phase A: parallel scalar gather + weight precompute ----
    for (int i = threadIdx.x; i < deg * 16; i += 256) {
        int p = i >> 4, g = i & 15;
        const int* xg = x + (gset + g) * NODES;
        int s   = sl[p];
        int tok = xg[s];
        int tkn = xg[n];
        float4 ts4 = *(const float4*)(g_ts + tok * HEADS);
        float4 td4 = *(const float4*)(g_td + tkn * HEADS);
        float4 w4;
        w4.x = __expf(lrelu(ts4.x + td4.x));
        w4.y = __expf(lrelu(ts4.y + td4.y));
        w4.z = __expf(lrelu(ts4.z + td4.z));
        w4.w = __expf(lrelu(ts4.w + td4.w));
        *(float4*)(l_w + (size_t)i * 4) = w4;
        l_tok[i] = tok;
    }
    __syncthreads();

    // ---- phase B: per-(graph, head, col-slice) accumulate ----
    int gl = threadIdx.x >> 4;               // local graph 0..15
    int t  = threadIdx.x & 15;
    int h  = t >> 2;
    int j0 = t * 8;

    const int* xg = x + (gset + gl) * NODES;
    int tokn = xg[n];
    float ad = g_td[tokn * HEADS + h];

    // self loop
    float wself = __expf(lrelu(g_ts[tokn * HEADS + h] + ad));
    float ssum = wself;
    float a0, a1, a2, a3, a4, a5, a6, a7;
    {
        uint4 r = *(const uint4*)(g_tb + tokn * HC + j0);
        a0 = wself * bflo(r.x); a1 = wself * bfhi(r.x);
        a2 = wself * bflo(r.y); a3 = wself * bfhi(r.y);
        a4 = wself * bflo(r.z); a5 = wself * bfhi(r.z);
        a6 = wself * bflo(r.w); a7 = wself * bfhi(r.w);
    }

    if (deg > 0) {
        int last = deg - 1;
        // preload: rows p..p+3, tokens p+4,p+5, weights p,p+1 (clamped)
        int q0 = l_tok[0 * 16 + gl];
        int q1 = l_tok[min(1, last) * 16 + gl];
        int q2 = l_tok[min(2, last) * 16 + gl];
        int q3 = l_tok[min(3, last) * 16 + gl];
        uint4 R0 = *(const uint4*)(g_tb + q0 * HC + j0);
        uint4 R1 = *(const uint4*)(g_tb + q1 * HC + j0);
        uint4 R2 = *(const uint4*)(g_tb + q2 * HC + j0);
        uint4 R3 = *(const uint4*)(g_tb + q3 * HC + j0);
        int q4 = l_tok[min(4, last) * 16 + gl];
        int q5 = l_tok[min(5, last) * 16 + gl];
        float wA = l_w[(0 * 16 + gl) * 4 + h];
        float wB = l_w[(min(1, last) * 16 + gl) * 4 + h];

        for (int p = 0; p <= last; ++p) {
            uint4 Rn = *(const uint4*)(g_tb + q4 * HC + j0);      // row p+4
            int   qn = l_tok[min(p + 6, last) * 16 + gl];         // tok p+6
            float wn = l_w[(min(p + 2, last) * 16 + gl) * 4 + h]; // w   p+2

            ssum += wA;
            a0 = fmaf(wA, bflo(R0.x), a0); a1 = fmaf(wA, bfhi(R0.x), a1);
            a2 = fmaf(wA, bflo(R0.y), a2); a3 = fmaf(wA, bfhi(R0.y), a3);
            a4 = fmaf(wA, bflo(R0.z), a4); a5 = fmaf(wA, bfhi(R0.z), a5);
            a6 = fmaf(wA, bflo(R0.w), a6); a7 = fmaf(wA, bfhi(R0.w), a7);

            R0 = R1; R1 = R2; R2 = R3; R3 = Rn;
            q4 = q5; q5 = qn;
            wA = wB; wB = wn;
        }
    }

    float inv = 1.f / ssum;
    const float4* bp = (const float4*)(bias + j0);
    float4 b0 = bp[0], b1 = bp[1];
    float4 o0, o1;
    o0.x = fmaf(a0, inv, b0.x); o0.y = fmaf(a1, inv, b0.y);
    o0.z = fmaf(a2, inv, b0.z); o0.w = fmaf(a3, inv, b0.w);
    o1.x = fmaf(a4, inv, b1.x); o1.y = fmaf(a5, inv, b1.y);
    o1.z = fmaf(a6, inv, b1.z); o1.w = fmaf(a7, inv, b1.w);

    float4* op = (float4*)(out + ((size_t)(gset + gl) * NODES + n) * HC + j0);
    op[0] = o0;
    op[1] = o1;
}

// ---------------------------------------------------------------------------
// Launch 3: restore g_cnt == 0 invariant for the next call.
// ---------------------------------------------------------------------------
__global__ void k_reset()
{
    int i = blockIdx.x * 256 + threadIdx.x;
    if (i < NODES) g_cnt[i] = 0;
}

// ---------------------------------------------------------------------------
extern "C" void kernel_launch(void* const* d_in, const int* in_sizes, int n_in,
                              void* d_out, int out_size, void* d_ws, size_t ws_size,
                              hipStream_t stream)
{
    (void)in_sizes; (void)n_in; (void)out_size; (void)d_ws; (void)ws_size;

    const int*   x    = (const int*)d_in[0];     // [G, N]
    const int*   adj  = (const int*)d_in[1];     // [2, E]
    const float* emb  = (const float*)d_in[2];   // [N, EMB]
    const float* lw   = (const float*)d_in[3];   // [EMB, H*C]
    const float* asrc = (const float*)d_in[4];   // [H, C]
    const float* adst = (const float*)d_in[5];   // [H, C]
    const float* bias = (const float*)d_in[6];   // [H*C]
    float*       out  = (float*)d_out;           // [G, N, H*C] fp32

    k_prep <<<NODES / 2 + NEDGE / 256, 256, 0, stream>>>(emb, lw, asrc, adst, adj);
    k_main <<<GRAPHS * NODES / 16, 256, 0, stream>>>(x, bias, out);
    k_reset<<<(NODES + 255) / 256, 256, 0, stream>>>();
}

// Round 14
// 106.754 us; speedup vs baseline: 1.0268x; 1.0268x over previous
//
#include <hip/hip_runtime.h>
#include <hip/hip_bf16.h>

// B=4, D=8 -> G=32 graphs, N=2000 nodes, E=32000 edges (+N self loops),
// EMB=32, H=4 heads, C=32 -> H*C=128. fp32 I/O (verified round 6).
// R10 finding: hipLaunchCooperativeKernel silently no-ops here.
// R11 finding: ~50 us/call is harness poison/restore (256 MiB ws fill) — fixed.
// R13: 2-launch structure; k_main self-resets g_cnt (block-exclusive access).
#define NODES  2000
#define GRAPHS 32
#define NEDGE  32000
#define EMBD   32
#define HEADS  4
#define CDIM   32
#define HC     128
#define DCAP   64            // per-dst slot cap; Poisson(16) tail @64 ~1e-20
#define NEG_SLOPE 0.2f

// Static device scratch. Invariant: g_cnt == 0 at entry of every call
// (.bss-zeroed at load; k_main restores it each call after consuming it).
__device__ unsigned short g_tb[NODES * HC];     // t rows, bf16 (512 KB)
__device__ float g_ts[NODES * HEADS];           // <t[v,h,:], att_src[h,:]>
__device__ float g_td[NODES * HEADS];           // <t[v,h,:], att_dst[h,:]>
__device__ int   g_cnt[NODES];                  // in-degree / cursor
__device__ int   g_slot[NODES * DCAP];          // src ids per dst

__device__ __forceinline__ float lrelu(float z) {
    return z >= 0.f ? z : NEG_SLOPE * z;
}
__device__ __forceinline__ float bflo(unsigned int w) {
    return __uint_as_float(w << 16);
}
__device__ __forceinline__ float bfhi(unsigned int w) {
    return __uint_as_float(w & 0xffff0000u);
}

// ---------------------------------------------------------------------------
// Launch 1: token tables (blocks 0..999) CONCURRENT with edge slot-scatter
// (blocks 1000..1124).
// ---------------------------------------------------------------------------
__global__ __launch_bounds__(256) void k_prep(
    const float* __restrict__ emb,
    const float* __restrict__ lw,
    const float* __restrict__ asrc,
    const float* __restrict__ adst,
    const int*   __restrict__ adj)
{
    if (blockIdx.x >= NODES / 2) {
        int e = (blockIdx.x - NODES / 2) * 256 + threadIdx.x;   // exact 32000
        int s = adj[e];
        int d = adj[NEDGE + e];
        int pos = atomicAdd(&g_cnt[d], 1);
        if (pos < DCAP) g_slot[d * DCAP + pos] = s;
        return;
    }

    int v = blockIdx.x * 2 + (threadIdx.x >> 7);
    int j = threadIdx.x & 127;          // h = j>>5, c = j&31

    float acc = 0.f;
#pragma unroll
    for (int d = 0; d < EMBD; ++d)
        acc = fmaf(emb[v * EMBD + d], lw[d * HC + j], acc);
    g_tb[v * HC + j] = __bfloat16_as_ushort(__float2bfloat16(acc));

    int h = j >> 5, c = j & 31;
    float ps = acc * asrc[h * CDIM + c];
    float pd = acc * adst[h * CDIM + c];
#pragma unroll
    for (int m = 16; m >= 1; m >>= 1) {
        ps += __shfl_xor(ps, m);
        pd += __shfl_xor(pd, m);
    }
    if (c == 0) {
        g_ts[v * HEADS + h] = ps;
        g_td[v * HEADS + h] = pd;
    }
}

// ---------------------------------------------------------------------------
// Launch 2: main GAT kernel. ONE block per node n (512 threads = 8 waves):
// all 32 graphs, 16 threads each (thread t: head h=t>>2, cols j0=t*8 -> one
// dwordx4 per bf16 row). deg/slots are block-uniform scalars.
// Phase A: all per-edge scalars — token ids AND softmax weights
// w = exp(lrelu(ts_src + td_dst)) — computed in parallel (deg*32 independent
// (p,g) pairs) into LDS. One barrier. Then thread 0 resets g_cnt[n] (safe:
// every thread read deg before the barrier; no other block touches it).
// Phase B: edge loop with NO dependent L2 chain: tokens from LDS (+6),
// rows prefetched +4 (registers), weights from LDS (+2); trips == deg.
// Single-pass softmax (|logit| < ~15 -> exp safe; ratio identical).
// LDS 40 KB -> 4 blocks/CU -> full 32-wave occupancy.
// ---------------------------------------------------------------------------
__global__ __launch_bounds__(512) void k_main(
    const int* __restrict__ x,
    const float* __restrict__ bias,
    float* __restrict__ out)
{
    __shared__ float l_w[DCAP * 32 * 4];    // [(p*32+g)*4 + h]  32 KB
    __shared__ int   l_tok[DCAP * 32];      // [p*32 + g]         8 KB

    int n = blockIdx.x;                      // block-uniform node

    int deg = g_cnt[n];                      // scalar
    if (deg > DCAP) deg = DCAP;
    const int* sl = g_slot + n * DCAP;       // scalar base

    // ---- phase A: parallel scalar gather + weight precompute ----
    for (int i = threadIdx.x; i < deg * 32; i += 512) {
        int p = i >> 5, g = i & 31;
        const int* xg = x + g * NODES;
        int s   = sl[p];
        int tok = xg[s];
        int tkn = xg[n];
        float4 ts4 = *(const float4*)(g_ts + tok * HEADS);
        float4 td4 = *(const float4*)(g_td + tkn * HEADS);
        float4 w4;
        w4.x = __expf(lrelu(ts4.x + td4.x));
        w4.y = __expf(lrelu(ts4.y + td4.y));
        w4.z = __expf(lrelu(ts4.z + td4.z));
        w4.w = __expf(lrelu(ts4.w + td4.w));
        *(float4*)(l_w + (size_t)i * 4) = w4;
        l_tok[i] = tok;
    }
    __syncthreads();

    // reset for next call: all threads have read g_cnt[n] before the barrier;
    // this is the only block that touches index n in this kernel.
    if (threadIdx.x == 0) g_cnt[n] = 0;

    // ---- phase B: per-(graph, head, col-slice) accumulate ----
    int gl = threadIdx.x >> 4;               // graph 0..31
    int t  = threadIdx.x & 15;
    int h  = t >> 2;
    int j0 = t * 8;

    const int* xg = x + gl * NODES;
    int tokn = xg[n];
    float ad = g_td[tokn * HEADS + h];

    // self loop
    float wself = __expf(lrelu(g_ts[tokn * HEADS + h] + ad));
    float ssum = wself;
    float a0, a1, a2, a3, a4, a5, a6, a7;
    {
        uint4 r = *(const uint4*)(g_tb + tokn * HC + j0);
        a0 = wself * bflo(r.x); a1 = wself * bfhi(r.x);
        a2 = wself * bflo(r.y); a3 = wself * bfhi(r.y);
        a4 = wself * bflo(r.z); a5 = wself * bfhi(r.z);
        a6 = wself * bflo(r.w); a7 = wself * bfhi(r.w);
    }

    if (deg > 0) {
        int last = deg - 1;
        // preload: rows p..p+3, tokens p+4,p+5, weights p,p+1 (clamped)
        int q0 = l_tok[0 * 32 + gl];
        int q1 = l_tok[min(1, last) * 32 + gl];
        int q2 = l_tok[min(2, last) * 32 + gl];
        int q3 = l_tok[min(3, last) * 32 + gl];
        uint4 R0 = *(const uint4*)(g_tb + q0 * HC + j0);
        uint4 R1 = *(const uint4*)(g_tb + q1 * HC + j0);
        uint4 R2 = *(const uint4*)(g_tb + q2 * HC + j0);
        uint4 R3 = *(const uint4*)(g_tb + q3 * HC + j0);
        int q4 = l_tok[min(4, last) * 32 + gl];
        int q5 = l_tok[min(5, last) * 32 + gl];
        float wA = l_w[(0 * 32 + gl) * 4 + h];
        float wB = l_w[(min(1, last) * 32 + gl) * 4 + h];

        for (int p = 0; p <= last; ++p) {
            uint4 Rn = *(const uint4*)(g_tb + q4 * HC + j0);      // row p+4
            int   qn = l_tok[min(p + 6, last) * 32 + gl];         // tok p+6
            float wn = l_w[(min(p + 2, last) * 32 + gl) * 4 + h]; // w   p+2

            ssum += wA;
            a0 = fmaf(wA, bflo(R0.x), a0); a1 = fmaf(wA, bfhi(R0.x), a1);
            a2 = fmaf(wA, bflo(R0.y), a2); a3 = fmaf(wA, bfhi(R0.y), a3);
            a4 = fmaf(wA, bflo(R0.z), a4); a5 = fmaf(wA, bfhi(R0.z), a5);
            a6 = fmaf(wA, bflo(R0.w), a6); a7 = fmaf(wA, bfhi(R0.w), a7);

            R0 = R1; R1 = R2; R2 = R3; R3 = Rn;
            q4 = q5; q5 = qn;
            wA = wB; wB = wn;
        }
    }

    float inv = 1.f / ssum;
    const float4* bp = (const float4*)(bias + j0);
    float4 b0 = bp[0], b1 = bp[1];
    float4 o0, o1;
    o0.x = fmaf(a0, inv, b0.x); o0.y = fmaf(a1, inv, b0.y);
    o0.z = fmaf(a2, inv, b0.z); o0.w = fmaf(a3, inv, b0.w);
    o1.x = fmaf(a4, inv, b1.x); o1.y = fmaf(a5, inv, b1.y);
    o1.z = fmaf(a6, inv, b1.z); o1.w = fmaf(a7, inv, b1.w);

    float4* op = (float4*)(out + ((size_t)gl * NODES + n) * HC + j0);
    op[0] = o0;
    op[1] = o1;
}

// ---------------------------------------------------------------------------
extern "C" void kernel_launch(void* const* d_in, const int* in_sizes, int n_in,
                              void* d_out, int out_size, void* d_ws, size_t ws_size,
                              hipStream_t stream)
{
    (void)in_sizes; (void)n_in; (void)out_size; (void)d_ws; (void)ws_size;

    const int*   x    = (const int*)d_in[0];     // [G, N]
    const int*   adj  = (const int*)d_in[1];     // [2, E]
    const float* emb  = (const float*)d_in[2];   // [N, EMB]
    const float* lw   = (const float*)d_in[3];   // [EMB, H*C]
    const float* asrc = (const float*)d_in[4];   // [H, C]
    const float* adst = (const float*)d_in[5];   // [H, C]
    const float* bias = (const float*)d_in[6];   // [H*C]
    float*       out  = (float*)d_out;           // [G, N, H*C] fp32

    k_prep<<<NODES / 2 + NEDGE / 256, 256, 0, stream>>>(emb, lw, asrc, adst, adj);
    k_main<<<NODES, 512, 0, stream>>>(x, bias, out);
}